// Round 2
// baseline (655.596 us; speedup 1.0000x reference)
//
#include <hip/hip_runtime.h>

// KVCache update, MI355X (gfx950). All tensors fp32 (per reference jnp.float32).
// Static shapes: B=8, S=4096, H=32, D=128, L=128, IDX=1024, RESET=0 -> to_idx=1152.
// out[b,s,h,d] = cache[b,s,h,d] + (s >= IDX ? x[b, s-IDX, h, d] : 0.f)
// masks / index / reset_index inputs are dead code for the returned content.
//
// V2b: 8 s-rows per thread (8 independent 16B loads in flight per lane),
//      8x fewer blocks (4608 vs 36864), nontemporal loads/stores (pure
//      streaming traffic, touched exactly once). Uses clang ext_vector
//      float4 (native vector) so __builtin_nontemporal_* accepts it.

#define Bc   8
#define Sc   4096
#define Hc   32
#define Dc   128
#define Lc   128
#define IDXc 1024
#define TOI  (IDXc + Lc)            // 1152
#define VPR  ((Hc * Dc) / 4)        // 1024 float4 vectors per (b,s) row
#define SPT  8                      // s-rows per thread (IDXc % SPT == 0)

typedef float f4 __attribute__((ext_vector_type(4)));

__global__ __launch_bounds__(256) void kv_update_kernel(
    const f4* __restrict__ cache,   // [B, S, VPR]
    const f4* __restrict__ x,       // [B, L, VPR]
    f4* __restrict__ out)           // [B, TOI, VPR]
{
    const int vec = blockIdx.x * 256 + threadIdx.x;  // 0..1023
    const int s0  = blockIdx.y * SPT;                // 0, 8, ..., 1144
    const int b   = blockIdx.z;                      // 0..7

    const f4* cp = cache + (size_t)(b * Sc  + s0) * VPR + vec;
    f4*       op = out   + (size_t)(b * TOI + s0) * VPR + vec;

    f4 v[SPT];
#pragma unroll
    for (int i = 0; i < SPT; ++i)
        v[i] = __builtin_nontemporal_load(cp + i * VPR);

    if (s0 >= IDXc) {   // whole tile is in the add region (block-uniform)
        const f4* xp = x + (size_t)(b * Lc + (s0 - IDXc)) * VPR + vec;
#pragma unroll
        for (int i = 0; i < SPT; ++i) {
            const f4 xv = __builtin_nontemporal_load(xp + i * VPR);
            v[i] += xv;
        }
    }

#pragma unroll
    for (int i = 0; i < SPT; ++i)
        __builtin_nontemporal_store(v[i], op + i * VPR);
}

extern "C" void kernel_launch(void* const* d_in, const int* in_sizes, int n_in,
                              void* d_out, int out_size, void* d_ws, size_t ws_size,
                              hipStream_t stream) {
    // Input order (setup_inputs): cache, cache_mask, x, mask, index, reset_index.
    const f4* cache = (const f4*)d_in[0];
    const f4* x     = (const f4*)d_in[2];
    f4*       out   = (f4*)d_out;

    dim3 grid(VPR / 256, TOI / SPT, Bc);   // (4, 144, 8) = 4608 blocks of 256
    dim3 block(256, 1, 1);
    kv_update_kernel<<<grid, block, 0, stream>>>(cache, x, out);
}